// Round 1
// baseline (352.130 us; speedup 1.0000x reference)
//
#include <hip/hip_runtime.h>
#include <math.h>

// HierarchicalRouter: x[32768][2048] fp32, W1[8][2048], W2[8][2048].
// Per token: 16 dots -> top2(groups) x top2(experts) -> 4 global indices
// (g*8+e) + softmax over the 4 combined (sum) scores.
// Output buffer (float32 throughout): [0,131072)      = topk_idx as floats
//                                     [131072,262144) = softmax weights
//
// R5: weights staged in LDS (128 KB/block); block = 512 thr (8 waves),
// 1 block/CU, 128 tokens/block, 256 blocks. launch_bounds(512,2) -> 256 VGPR.
//
// R6 (this round): the timed 341.6 us = ~321 us harness poison fills (2x 1GiB,
// top-5 rocprof rows) + ~20.6 us router. At 20.6 us the router reads x at
// ~12.8 TB/s (L3-resident) -> it is VALU-ISSUE-bound, not memory-bound:
// 8192 v_fmac/thread = 13.7 us chip-wide issue floor. Fix: halve FMA issue
// slots with v_pk_fma_f32 by pairing over d. acc becomes float2 (two partial
// sums per score, folded at the end); the .lo/.hi halves of each f4 are
// already aligned VGPR pairs so the packing costs zero moves. Weights are
// consumed in two halves of 8 experts to keep live VGPRs ~208 < 256.

#define D       2048
#define NTOK    32768
#define IDX_REG 131072   // NTOK*4, start of weights region

typedef float f4 __attribute__((ext_vector_type(4)));
typedef float f2 __attribute__((ext_vector_type(2)));

template <int T>
__device__ __forceinline__ void load_sc(const float (&red)[16][4], float (&sc)[16]) {
#pragma unroll
    for (int k = 0; k < 16; ++k) sc[k] = red[k][T];
}

__global__ __launch_bounds__(512, 2) void router_kernel(
    const float* __restrict__ x,
    const float* __restrict__ W1,
    const float* __restrict__ W2,
    float* __restrict__ out)
{
    __shared__ float w_lds[32768];   // [row 0..15][2048], rows 8..15 = W2

    const int tid  = threadIdx.x;
    const int lane = tid & 63;
    const int g    = lane >> 4;                 // group 0..3
    const int j    = lane & 15;                 // lane in group
    const int wave = (blockIdx.x << 3) | (tid >> 6);   // 0..2047
    const int tok_base = wave * 16 + g * 4;     // 4 tokens/group

    // Stage W1+W2 into LDS (32768 floats = 8192 f4; 16 f4 per thread).
    {
        f4* lds4 = (f4*)w_lds;
        const f4* w1v = (const f4*)W1;
        const f4* w2v = (const f4*)W2;
#pragma unroll
        for (int i = 0; i < 8; ++i) {
            int idx = tid + i * 512;
            lds4[idx]        = w1v[idx];
            lds4[4096 + idx] = w2v[idx];
        }
    }
    __syncthreads();

    // Packed accumulators: acc[k][t] holds {sum over even d-pairs, odd d-pairs}.
    f2 acc[16][4];
#pragma unroll
    for (int k = 0; k < 16; ++k)
#pragma unroll
        for (int t = 0; t < 4; ++t) acc[k][t] = (f2)(0.f);

    const float* xbase = x + (size_t)tok_base * D + (j << 2);

#pragma unroll 2
    for (int s = 0; s < 32; ++s) {
        const int d = s * 64 + (j << 2);

        f4 xv[4];
#pragma unroll
        for (int t = 0; t < 4; ++t)
            xv[t] = __builtin_nontemporal_load((const f4*)(xbase + t * D + s * 64));

        // Experts 0..7, then 8..15 (halved live range for wv).
#pragma unroll
        for (int h = 0; h < 2; ++h) {
            f4 wv[8];
#pragma unroll
            for (int k = 0; k < 8; ++k)
                wv[k] = *(const f4*)(w_lds + (h * 8 + k) * D + d);

#pragma unroll
            for (int k = 0; k < 8; ++k)
#pragma unroll
                for (int t = 0; t < 4; ++t) {
                    // two v_pk_fma_f32 per (k,t) per f4 chunk
                    acc[h * 8 + k][t] =
                        __builtin_elementwise_fma(wv[k].lo, xv[t].lo, acc[h * 8 + k][t]);
                    acc[h * 8 + k][t] =
                        __builtin_elementwise_fma(wv[k].hi, xv[t].hi, acc[h * 8 + k][t]);
                }
        }
    }

    // Fold the packed pair, then reduce across the 16 lanes of each group.
    float red[16][4];
#pragma unroll
    for (int k = 0; k < 16; ++k)
#pragma unroll
        for (int t = 0; t < 4; ++t) red[k][t] = acc[k][t].x + acc[k][t].y;

#pragma unroll
    for (int m = 1; m <= 8; m <<= 1)
#pragma unroll
        for (int k = 0; k < 16; ++k)
#pragma unroll
            for (int t = 0; t < 4; ++t)
                red[k][t] += __shfl_xor(red[k][t], m, 64);

    // Lanes 0..3 of each group finish one token each (compile-time column).
    if (j < 4) {
        float sc[16];
        if      (j == 0) load_sc<0>(red, sc);
        else if (j == 1) load_sc<1>(red, sc);
        else if (j == 2) load_sc<2>(red, sc);
        else             load_sc<3>(red, sc);

        const int token = tok_base + j;

        // top2 of group scores (earlier index wins ties, like lax.top_k)
        float bg0 = sc[0]; int gi0 = 0; float bg1 = -INFINITY; int gi1 = 0;
#pragma unroll
        for (int k = 1; k < 8; ++k) {
            float v = sc[k];
            if (v > bg0) { bg1 = bg0; gi1 = gi0; bg0 = v; gi0 = k; }
            else if (v > bg1) { bg1 = v; gi1 = k; }
        }
        // top2 of expert scores
        float be0 = sc[8]; int ei0 = 0; float be1 = -INFINITY; int ei1 = 0;
#pragma unroll
        for (int k = 1; k < 8; ++k) {
            float v = sc[8 + k];
            if (v > be0) { be1 = be0; ei1 = ei0; be0 = v; ei0 = k; }
            else if (v > be1) { be1 = v; ei1 = k; }
        }

        // combined scores; c0 = bg0+be0 is the max by construction
        float c0 = bg0 + be0, c1 = bg0 + be1, c2 = bg1 + be0, c3 = bg1 + be1;
        float e0 = 1.f;
        float e1 = __expf(c1 - c0);
        float e2 = __expf(c2 - c0);
        float e3 = __expf(c3 - c0);
        float inv = 1.f / (e0 + e1 + e2 + e3);

        float4 idxv = make_float4((float)(gi0 * 8 + ei0), (float)(gi0 * 8 + ei1),
                                  (float)(gi1 * 8 + ei0), (float)(gi1 * 8 + ei1));
        float4 wout = make_float4(e0 * inv, e1 * inv, e2 * inv, e3 * inv);

        *(float4*)(out + (size_t)token * 4)           = idxv;
        *(float4*)(out + IDX_REG + (size_t)token * 4) = wout;
    }
}

extern "C" void kernel_launch(void* const* d_in, const int* in_sizes, int n_in,
                              void* d_out, int out_size, void* d_ws, size_t ws_size,
                              hipStream_t stream) {
    const float* x  = (const float*)d_in[0];
    const float* W1 = (const float*)d_in[1];
    const float* W2 = (const float*)d_in[2];
    float* out = (float*)d_out;
    // 32768 tokens / 128 tokens-per-block = 256 blocks of 512 threads
    dim3 grid(256), block(512);
    hipLaunchKernelGGL(router_kernel, grid, block, 0, stream, x, W1, W2, out);
}

// Round 2
// 339.421 us; speedup vs baseline: 1.0374x; 1.0374x over previous
//
#include <hip/hip_runtime.h>
#include <math.h>

// HierarchicalRouter: x[32768][2048] fp32, W1[8][2048], W2[8][2048].
// Per token: 16 dots -> top2(groups) x top2(experts) -> 4 global indices
// (g*8+e) + softmax over the 4 combined (sum) scores.
// Output buffer (float32 throughout): [0,131072)      = topk_idx as floats
//                                     [131072,262144) = softmax weights
//
// R5 (best: 341.6 us total = ~321 us harness poison fills + ~20.6 us router):
// weights staged in LDS (128 KB/block) -> inner loop has only 4 global
// x-loads + 16 ds_read_b128 per step. Block = 512 thr (8 waves), 1 block/CU
// (LDS-forced), 128 tokens/block, 256 blocks exactly. launch_bounds(512,2)
// keeps the VGPR cap at 256 so a full iteration + prefetch stays in regs.
//
// R6 post-mortem (REVERTED): v_pk_fma_f32 via float2 accumulators regressed
// +10.5 us. (a) fp32 pipe is FLOP-limited: 157.3 TF == scalar v_fmac rate,
// packed gives no extra FLOPs; (b) splitting the 16-wide ds_read batch into
// two 8-wide halves broke LDS latency hiding; (c) router is L3-BW-bound
// anyway: 268 MB x / 20.6 us = 13.0 TB/s ~ Infinity Cache ceiling, above
// the 13.7 us VALU floor. R5 sits at max(FLOP, L3-BW) already.

#define D       2048
#define NTOK    32768
#define IDX_REG 131072   // NTOK*4, start of weights region

typedef float f4 __attribute__((ext_vector_type(4)));

template <int T>
__device__ __forceinline__ void load_sc(const float (&acc)[16][4], float (&sc)[16]) {
#pragma unroll
    for (int k = 0; k < 16; ++k) sc[k] = acc[k][T];
}

__global__ __launch_bounds__(512, 2) void router_kernel(
    const float* __restrict__ x,
    const float* __restrict__ W1,
    const float* __restrict__ W2,
    float* __restrict__ out)
{
    __shared__ float w_lds[32768];   // [row 0..15][2048], rows 8..15 = W2

    const int tid  = threadIdx.x;
    const int lane = tid & 63;
    const int g    = lane >> 4;                 // group 0..3
    const int j    = lane & 15;                 // lane in group
    const int wave = (blockIdx.x << 3) | (tid >> 6);   // 0..2047
    const int tok_base = wave * 16 + g * 4;     // 4 tokens/group

    // Stage W1+W2 into LDS (32768 floats = 8192 f4; 16 f4 per thread).
    {
        f4* lds4 = (f4*)w_lds;
        const f4* w1v = (const f4*)W1;
        const f4* w2v = (const f4*)W2;
#pragma unroll
        for (int i = 0; i < 8; ++i) {
            int idx = tid + i * 512;
            lds4[idx]        = w1v[idx];
            lds4[4096 + idx] = w2v[idx];
        }
    }
    __syncthreads();

    float acc[16][4];   // [expert_slot][token]
#pragma unroll
    for (int k = 0; k < 16; ++k)
#pragma unroll
        for (int t = 0; t < 4; ++t) acc[k][t] = 0.f;

    const float* xbase = x + (size_t)tok_base * D + (j << 2);

#pragma unroll 2
    for (int s = 0; s < 32; ++s) {
        const int d = s * 64 + (j << 2);

        f4 xv[4];
#pragma unroll
        for (int t = 0; t < 4; ++t)
            xv[t] = __builtin_nontemporal_load((const f4*)(xbase + t * D + s * 64));

        f4 wv[16];
#pragma unroll
        for (int k = 0; k < 16; ++k)
            wv[k] = *(const f4*)(w_lds + k * D + d);

#pragma unroll
        for (int k = 0; k < 16; ++k)
#pragma unroll
            for (int t = 0; t < 4; ++t) {
                acc[k][t] = fmaf(wv[k].x, xv[t].x, acc[k][t]);
                acc[k][t] = fmaf(wv[k].y, xv[t].y, acc[k][t]);
                acc[k][t] = fmaf(wv[k].z, xv[t].z, acc[k][t]);
                acc[k][t] = fmaf(wv[k].w, xv[t].w, acc[k][t]);
            }
    }

    // Reduce across the 16 lanes of each group (xor butterfly stays in-group).
#pragma unroll
    for (int m = 1; m <= 8; m <<= 1)
#pragma unroll
        for (int k = 0; k < 16; ++k)
#pragma unroll
            for (int t = 0; t < 4; ++t)
                acc[k][t] += __shfl_xor(acc[k][t], m, 64);

    // Lanes 0..3 of each group finish one token each (compile-time column).
    if (j < 4) {
        float sc[16];
        if      (j == 0) load_sc<0>(acc, sc);
        else if (j == 1) load_sc<1>(acc, sc);
        else if (j == 2) load_sc<2>(acc, sc);
        else             load_sc<3>(acc, sc);

        const int token = tok_base + j;

        // top2 of group scores (earlier index wins ties, like lax.top_k)
        float bg0 = sc[0]; int gi0 = 0; float bg1 = -INFINITY; int gi1 = 0;
#pragma unroll
        for (int k = 1; k < 8; ++k) {
            float v = sc[k];
            if (v > bg0) { bg1 = bg0; gi1 = gi0; bg0 = v; gi0 = k; }
            else if (v > bg1) { bg1 = v; gi1 = k; }
        }
        // top2 of expert scores
        float be0 = sc[8]; int ei0 = 0; float be1 = -INFINITY; int ei1 = 0;
#pragma unroll
        for (int k = 1; k < 8; ++k) {
            float v = sc[8 + k];
            if (v > be0) { be1 = be0; ei1 = ei0; be0 = v; ei0 = k; }
            else if (v > be1) { be1 = v; ei1 = k; }
        }

        // combined scores; c0 = bg0+be0 is the max by construction
        float c0 = bg0 + be0, c1 = bg0 + be1, c2 = bg1 + be0, c3 = bg1 + be1;
        float e0 = 1.f;
        float e1 = __expf(c1 - c0);
        float e2 = __expf(c2 - c0);
        float e3 = __expf(c3 - c0);
        float inv = 1.f / (e0 + e1 + e2 + e3);

        float4 idxv = make_float4((float)(gi0 * 8 + ei0), (float)(gi0 * 8 + ei1),
                                  (float)(gi1 * 8 + ei0), (float)(gi1 * 8 + ei1));
        float4 wout = make_float4(e0 * inv, e1 * inv, e2 * inv, e3 * inv);

        *(float4*)(out + (size_t)token * 4)           = idxv;
        *(float4*)(out + IDX_REG + (size_t)token * 4) = wout;
    }
}

extern "C" void kernel_launch(void* const* d_in, const int* in_sizes, int n_in,
                              void* d_out, int out_size, void* d_ws, size_t ws_size,
                              hipStream_t stream) {
    const float* x  = (const float*)d_in[0];
    const float* W1 = (const float*)d_in[1];
    const float* W2 = (const float*)d_in[2];
    float* out = (float*)d_out;
    // 32768 tokens / 128 tokens-per-block = 256 blocks of 512 threads
    dim3 grid(256), block(512);
    hipLaunchKernelGGL(router_kernel, grid, block, 0, stream, x, W1, W2, out);
}